// Round 1
// baseline (579.607 us; speedup 1.0000x reference)
//
#include <hip/hip_runtime.h>
#include <hip/hip_bf16.h>

typedef __bf16 bf16_t;
typedef __bf16 bf16x8 __attribute__((ext_vector_type(8)));
typedef float f32x4 __attribute__((ext_vector_type(4)));

#define SCALE_ 0.125f   // 64^-0.5
#define BATCH 4
#define NSEQ 2048
#define DMODEL 512
#define HEADS 8
#define DHEAD 64
#define QKVN 1536

// ---------------- convert kernels ----------------
__global__ __launch_bounds__(256) void cvt_bf16_kernel(const float* __restrict__ in,
                                                       bf16_t* __restrict__ out, int n4) {
  int i = blockIdx.x * 256 + threadIdx.x;
  if (i < n4) {
    float4 v = ((const float4*)in)[i];
    union { bf16_t b[4]; uint2 u; } pk;
    pk.b[0] = (bf16_t)v.x; pk.b[1] = (bf16_t)v.y;
    pk.b[2] = (bf16_t)v.z; pk.b[3] = (bf16_t)v.w;
    ((uint2*)out)[i] = pk.u;
  }
}

// in[R][C] fp32 -> out[C][R] bf16   (coalesced writes)
__global__ __launch_bounds__(256) void cvt_transpose_kernel(const float* __restrict__ in,
                                                            bf16_t* __restrict__ out, int R, int C) {
  int i = blockIdx.x * 256 + threadIdx.x;
  if (i < R * C) {
    int cc = i / R, rr = i - cc * R;
    out[(size_t)cc * R + rr] = (bf16_t)in[(size_t)rr * C + cc];
  }
}

// ---------------- GEMM: C[M,N] = A[M,K] * Bt[N,K]^T (+bias) ----------------
template<int BIAS, int OUTF32>
__global__ __launch_bounds__(256) void gemm_bt_kernel(const bf16_t* __restrict__ A,
    const bf16_t* __restrict__ Bt, void* __restrict__ Cout,
    const float* __restrict__ bias, int M, int N, int K) {
  __shared__ __align__(16) bf16_t As[64][72];
  __shared__ __align__(16) bf16_t Bs[64][72];
  const int tid = threadIdx.x;
  const int w = tid >> 6, lane = tid & 63, quad = lane >> 4, l16 = lane & 15;
  const int m0 = blockIdx.x * 64, n0 = blockIdx.y * 64;
  const int sr = tid >> 3, sg = tid & 7;
  f32x4 acc[4] = {};
  for (int k0 = 0; k0 < K; k0 += 64) {
    *(uint4*)&As[sr][sg * 8]      = *(const uint4*)&A[(size_t)(m0 + sr) * K + k0 + sg * 8];
    *(uint4*)&As[sr + 32][sg * 8] = *(const uint4*)&A[(size_t)(m0 + sr + 32) * K + k0 + sg * 8];
    *(uint4*)&Bs[sr][sg * 8]      = *(const uint4*)&Bt[(size_t)(n0 + sr) * K + k0 + sg * 8];
    *(uint4*)&Bs[sr + 32][sg * 8] = *(const uint4*)&Bt[(size_t)(n0 + sr + 32) * K + k0 + sg * 8];
    __syncthreads();
    bf16x8 a0 = *(const bf16x8*)&As[w * 16 + l16][quad * 8];
    bf16x8 a1 = *(const bf16x8*)&As[w * 16 + l16][32 + quad * 8];
#pragma unroll
    for (int nt = 0; nt < 4; nt++) {
      bf16x8 b0 = *(const bf16x8*)&Bs[nt * 16 + l16][quad * 8];
      bf16x8 b1 = *(const bf16x8*)&Bs[nt * 16 + l16][32 + quad * 8];
      acc[nt] = __builtin_amdgcn_mfma_f32_16x16x32_bf16(a0, b0, acc[nt], 0, 0, 0);
      acc[nt] = __builtin_amdgcn_mfma_f32_16x16x32_bf16(a1, b1, acc[nt], 0, 0, 0);
    }
    __syncthreads();
  }
#pragma unroll
  for (int nt = 0; nt < 4; nt++) {
    int col = n0 + nt * 16 + l16;
    float bv = BIAS ? bias[col] : 0.0f;
#pragma unroll
    for (int rr = 0; rr < 4; rr++) {
      int row = m0 + w * 16 + quad * 4 + rr;
      float v = acc[nt][rr] + bv;
      if (OUTF32) ((float*)Cout)[(size_t)row * N + col] = v;
      else        ((bf16_t*)Cout)[(size_t)row * N + col] = (bf16_t)v;
    }
  }
}

// ---------------- fused flash attention with conv-bias ----------------
// grid: B*32*8 blocks; bid = b*256 + it*8 + h  (h fastest: 8 heads share cd tile)
// block: 256 threads = 4 waves; wave w handles Q rows [it*64 + w*16, +16)
__global__ __launch_bounds__(256) void attn_kernel(const bf16_t* __restrict__ qkv,
    const float* __restrict__ cd, const float* __restrict__ rel_w,
    const float* __restrict__ rel_b, bf16_t* __restrict__ ao) {
  __shared__ __align__(16) bf16_t Ks[64][72];   // K tile: [jrel][d]
  __shared__ __align__(16) bf16_t Vts[64][72];  // V tile transposed: [d][jrel]
  __shared__ __align__(16) bf16_t Ps[64][72];   // P: [qrow(block)][jrel]
  const int tid = threadIdx.x;
  const int w = tid >> 6, lane = tid & 63, quad = lane >> 4, l16 = lane & 15;
  const int bid = blockIdx.x;
  const int h = bid & 7, it = (bid >> 3) & 31, b = bid >> 8;

  // Q fragments (A-layout): lane holds Q[row=l16][k=quad*8+j (+32)]
  const size_t qoff = (size_t)(b * NSEQ + it * 64 + w * 16 + l16) * QKVN + h * DHEAD;
  bf16x8 q0 = *(const bf16x8*)&qkv[qoff + quad * 8];
  bf16x8 q1 = *(const bf16x8*)&qkv[qoff + 32 + quad * 8];

  const float rw0 = rel_w[h * 3 + 0], rw1 = rel_w[h * 3 + 1], rw2 = rel_w[h * 3 + 2];
  const float rb = rel_b[h];

  f32x4 o[4] = {};
  float m_r[4], l_r[4];
#pragma unroll
  for (int r = 0; r < 4; r++) { m_r[r] = -1e30f; l_r[r] = 0.0f; }

  const int sr = tid >> 3, sg = tid & 7;
  const size_t kbase = (size_t)b * NSEQ * QKVN + DMODEL + h * DHEAD;       // K columns
  const size_t cdbase = (size_t)b * 3 * NSEQ * NSEQ;

  for (int jt = 0; jt < 32; jt++) {
    // ---- stage K tile and V^T tile ----
#pragma unroll
    for (int rep = 0; rep < 2; rep++) {
      int jrel = sr + rep * 32;
      const bf16_t* kptr = &qkv[kbase + (size_t)(jt * 64 + jrel) * QKVN + sg * 8];
      *(uint4*)&Ks[jrel][sg * 8] = *(const uint4*)kptr;
      union { bf16_t b[8]; uint4 u; } vt;
      vt.u = *(const uint4*)(kptr + DMODEL);   // V = K + 512 cols
#pragma unroll
      for (int e = 0; e < 8; e++) Vts[sg * 8 + e][jrel] = vt.b[e];
    }
    __syncthreads();

    // ---- S = Q * K^T (wave: 16 rows x 64 cols) ----
    f32x4 s[4] = {};
#pragma unroll
    for (int ct = 0; ct < 4; ct++) {
      bf16x8 b0 = *(const bf16x8*)&Ks[ct * 16 + l16][quad * 8];
      bf16x8 b1 = *(const bf16x8*)&Ks[ct * 16 + l16][32 + quad * 8];
      s[ct] = __builtin_amdgcn_mfma_f32_16x16x32_bf16(q0, b0, s[ct], 0, 0, 0);
      s[ct] = __builtin_amdgcn_mfma_f32_16x16x32_bf16(q1, b1, s[ct], 0, 0, 0);
    }

    // ---- scale + conv bias (fp32, straight from centroid_delta) ----
    const int row0 = it * 64 + w * 16 + quad * 4;
    const int col0 = jt * 64 + l16;
    float sv[4][4];
#pragma unroll
    for (int ct = 0; ct < 4; ct++) {
      int col = col0 + ct * 16;
#pragma unroll
      for (int r = 0; r < 4; r++) {
        size_t ci = cdbase + (size_t)(row0 + r) * NSEQ + col;
        float bias = rw0 * cd[ci] + rw1 * cd[ci + (size_t)NSEQ * NSEQ]
                   + rw2 * cd[ci + (size_t)2 * NSEQ * NSEQ] + rb;
        sv[ct][r] = s[ct][r] * SCALE_ + bias;
      }
    }

    // ---- online softmax (per quad-row; stats uniform across 16 lanes of quad) ----
#pragma unroll
    for (int r = 0; r < 4; r++) {
      float mx = fmaxf(fmaxf(sv[0][r], sv[1][r]), fmaxf(sv[2][r], sv[3][r]));
#pragma unroll
      for (int off = 8; off >= 1; off >>= 1) mx = fmaxf(mx, __shfl_xor(mx, off, 64));
      float mnew = fmaxf(m_r[r], mx);
      float alpha = __expf(m_r[r] - mnew);
      float rsum = 0.0f;
#pragma unroll
      for (int ct = 0; ct < 4; ct++) {
        float p = __expf(sv[ct][r] - mnew);
        sv[ct][r] = p; rsum += p;
      }
#pragma unroll
      for (int off = 8; off >= 1; off >>= 1) rsum += __shfl_xor(rsum, off, 64);
      l_r[r] = l_r[r] * alpha + rsum;
      m_r[r] = mnew;
#pragma unroll
      for (int dt = 0; dt < 4; dt++) o[dt][r] *= alpha;
    }

    // ---- P: C-layout -> LDS -> A-layout (wave-private slice, no barrier needed) ----
#pragma unroll
    for (int ct = 0; ct < 4; ct++)
#pragma unroll
      for (int rr = 0; rr < 4; rr++)
        Ps[w * 16 + quad * 4 + rr][ct * 16 + l16] = (bf16_t)sv[ct][rr];

    bf16x8 p0 = *(const bf16x8*)&Ps[w * 16 + l16][quad * 8];
    bf16x8 p1 = *(const bf16x8*)&Ps[w * 16 + l16][32 + quad * 8];
#pragma unroll
    for (int dt = 0; dt < 4; dt++) {
      bf16x8 v0 = *(const bf16x8*)&Vts[dt * 16 + l16][quad * 8];
      bf16x8 v1 = *(const bf16x8*)&Vts[dt * 16 + l16][32 + quad * 8];
      o[dt] = __builtin_amdgcn_mfma_f32_16x16x32_bf16(p0, v0, o[dt], 0, 0, 0);
      o[dt] = __builtin_amdgcn_mfma_f32_16x16x32_bf16(p1, v1, o[dt], 0, 0, 0);
    }
    __syncthreads();   // protect Ks/Vts before next stage
  }

  // ---- epilogue: normalize and store [row, h*64+d] bf16 ----
#pragma unroll
  for (int dt = 0; dt < 4; dt++) {
    int col = h * DHEAD + dt * 16 + l16;
#pragma unroll
    for (int rr = 0; rr < 4; rr++) {
      int row = b * NSEQ + it * 64 + w * 16 + quad * 4 + rr;
      ao[(size_t)row * DMODEL + col] = (bf16_t)(o[dt][rr] / l_r[rr]);
    }
  }
}

// ---------------- launch ----------------
extern "C" void kernel_launch(void* const* d_in, const int* in_sizes, int n_in,
                              void* d_out, int out_size, void* d_ws, size_t ws_size,
                              hipStream_t stream) {
  const float* x     = (const float*)d_in[0];
  const float* cd    = (const float*)d_in[1];
  const float* Wqkv  = (const float*)d_in[2];
  const float* Wout  = (const float*)d_in[3];
  const float* bout  = (const float*)d_in[4];
  const float* rel_w = (const float*)d_in[5];
  const float* rel_b = (const float*)d_in[6];
  float* out = (float*)d_out;

  char* ws = (char*)d_ws;
  const size_t M = (size_t)BATCH * NSEQ;                 // 8192
  bf16_t* xb    = (bf16_t*)ws;                           // 8192*512*2   = 8388608
  bf16_t* WqkvT = (bf16_t*)(ws + 8388608);               // 1536*512*2   = 1572864
  bf16_t* WoutT = (bf16_t*)(ws + 8388608 + 1572864);     // 512*512*2    = 524288
  bf16_t* qkv   = (bf16_t*)(ws + 8388608 + 1572864 + 524288);            // 8192*1536*2 = 25165824
  bf16_t* ao    = (bf16_t*)(ws + 8388608 + 1572864 + 524288 + 25165824); // 8192*512*2  = 8388608

  // converts
  cvt_bf16_kernel<<<(int)(M * DMODEL / 4 / 256), 256, 0, stream>>>(x, xb, (int)(M * DMODEL / 4));
  cvt_transpose_kernel<<<(DMODEL * QKVN) / 256, 256, 0, stream>>>(Wqkv, WqkvT, DMODEL, QKVN);
  cvt_transpose_kernel<<<(DMODEL * DMODEL) / 256, 256, 0, stream>>>(Wout, WoutT, DMODEL, DMODEL);

  // qkv = x @ Wqkv   -> bf16 [8192, 1536]
  gemm_bt_kernel<0, 0><<<dim3(M / 64, QKVN / 64), 256, 0, stream>>>(
      xb, WqkvT, (void*)qkv, nullptr, (int)M, QKVN, DMODEL);

  // fused attention -> ao bf16 [8192, 512]
  attn_kernel<<<BATCH * 32 * HEADS, 256, 0, stream>>>(qkv, cd, rel_w, rel_b, ao);

  // out = ao @ Wout + bout -> fp32 [8192, 512]
  gemm_bt_kernel<1, 1><<<dim3(M / 64, DMODEL / 64), 256, 0, stream>>>(
      ao, WoutT, (void*)out, bout, (int)M, DMODEL, DMODEL);
}

// Round 2
// 512.246 us; speedup vs baseline: 1.1315x; 1.1315x over previous
//
#include <hip/hip_runtime.h>
#include <hip/hip_bf16.h>

typedef __bf16 bf16_t;
typedef __bf16 bf16x8 __attribute__((ext_vector_type(8)));
typedef float f32x4 __attribute__((ext_vector_type(4)));

#define SCALE_ 0.125f   // 64^-0.5
#define BATCH 4
#define NSEQ 2048
#define DMODEL 512
#define HEADS 8
#define DHEAD 64
#define QKVN 1536
#define NN (NSEQ * NSEQ)

// ---------------- convert kernels ----------------
__global__ __launch_bounds__(256) void cvt_bf16_kernel(const float* __restrict__ in,
                                                       bf16_t* __restrict__ out, int n4) {
  int i = blockIdx.x * 256 + threadIdx.x;
  if (i < n4) {
    float4 v = ((const float4*)in)[i];
    union { bf16_t b[4]; uint2 u; } pk;
    pk.b[0] = (bf16_t)v.x; pk.b[1] = (bf16_t)v.y;
    pk.b[2] = (bf16_t)v.z; pk.b[3] = (bf16_t)v.w;
    ((uint2*)out)[i] = pk.u;
  }
}

// in[R][C] fp32 -> out[C][R] bf16   (coalesced writes)
__global__ __launch_bounds__(256) void cvt_transpose_kernel(const float* __restrict__ in,
                                                            bf16_t* __restrict__ out, int R, int C) {
  int i = blockIdx.x * 256 + threadIdx.x;
  if (i < R * C) {
    int cc = i / R, rr = i - cc * R;
    out[(size_t)cc * R + rr] = (bf16_t)in[(size_t)rr * C + cc];
  }
}

// ---------------- GEMM: C[M,N] = A[M,K] * Bt[N,K]^T (+bias) ----------------
template<int BIAS, int OUTF32>
__global__ __launch_bounds__(256) void gemm_bt_kernel(const bf16_t* __restrict__ A,
    const bf16_t* __restrict__ Bt, void* __restrict__ Cout,
    const float* __restrict__ bias, int M, int N, int K) {
  __shared__ __align__(16) bf16_t As[64][72];
  __shared__ __align__(16) bf16_t Bs[64][72];
  const int tid = threadIdx.x;
  const int w = tid >> 6, lane = tid & 63, quad = lane >> 4, l16 = lane & 15;
  const int m0 = blockIdx.x * 64, n0 = blockIdx.y * 64;
  const int sr = tid >> 3, sg = tid & 7;
  f32x4 acc[4] = {};
  for (int k0 = 0; k0 < K; k0 += 64) {
    *(uint4*)&As[sr][sg * 8]      = *(const uint4*)&A[(size_t)(m0 + sr) * K + k0 + sg * 8];
    *(uint4*)&As[sr + 32][sg * 8] = *(const uint4*)&A[(size_t)(m0 + sr + 32) * K + k0 + sg * 8];
    *(uint4*)&Bs[sr][sg * 8]      = *(const uint4*)&Bt[(size_t)(n0 + sr) * K + k0 + sg * 8];
    *(uint4*)&Bs[sr + 32][sg * 8] = *(const uint4*)&Bt[(size_t)(n0 + sr + 32) * K + k0 + sg * 8];
    __syncthreads();
    bf16x8 a0 = *(const bf16x8*)&As[w * 16 + l16][quad * 8];
    bf16x8 a1 = *(const bf16x8*)&As[w * 16 + l16][32 + quad * 8];
#pragma unroll
    for (int nt = 0; nt < 4; nt++) {
      bf16x8 b0 = *(const bf16x8*)&Bs[nt * 16 + l16][quad * 8];
      bf16x8 b1 = *(const bf16x8*)&Bs[nt * 16 + l16][32 + quad * 8];
      acc[nt] = __builtin_amdgcn_mfma_f32_16x16x32_bf16(a0, b0, acc[nt], 0, 0, 0);
      acc[nt] = __builtin_amdgcn_mfma_f32_16x16x32_bf16(a1, b1, acc[nt], 0, 0, 0);
    }
    __syncthreads();
  }
#pragma unroll
  for (int nt = 0; nt < 4; nt++) {
    int col = n0 + nt * 16 + l16;
    float bv = BIAS ? bias[col] : 0.0f;
#pragma unroll
    for (int rr = 0; rr < 4; rr++) {
      int row = m0 + w * 16 + quad * 4 + rr;
      float v = acc[nt][rr] + bv;
      if (OUTF32) ((float*)Cout)[(size_t)row * N + col] = v;
      else        ((bf16_t*)Cout)[(size_t)row * N + col] = (bf16_t)v;
    }
  }
}

// ---------------- fused flash attention with conv-bias ----------------
// grid: 1024 blocks; bid = h*128 + b*32 + it
//   -> the 8 head-siblings sharing one cd tile differ by 128 (= 0 mod 8),
//      i.e. land on the SAME XCD under round-robin XCD assignment, and all
//      1024 blocks are co-resident (4/CU) -> cd tile is fetched into that
//      XCD's L2 once instead of 8 HBM/LLC fetches.
// block: 256 threads = 4 waves; wave w handles Q rows [it*64 + w*16, +16)
__global__ __launch_bounds__(256, 4) void attn_kernel(const bf16_t* __restrict__ qkv,
    const float* __restrict__ cd, const float* __restrict__ rel_w,
    const float* __restrict__ rel_b, bf16_t* __restrict__ ao) {
  __shared__ __align__(16) bf16_t Ks[64][72];   // K tile: [jrel][d]
  __shared__ __align__(16) bf16_t Vts[64][72];  // V^T tile: [d][j], col XOR-swizzled
  __shared__ __align__(16) bf16_t Ps[64][72];   // P: [qrow][j], col XOR-swizzled
  const int tid = threadIdx.x;
  const int w = tid >> 6, lane = tid & 63, quad = lane >> 4, l16 = lane & 15;
  const int bid = blockIdx.x;
  const int h = bid >> 7, b = (bid >> 5) & 3, it = bid & 31;

  // Q fragments (A-layout): lane holds Q[row=l16][k=quad*8+j (+32)]
  const size_t qoff = (size_t)(b * NSEQ + it * 64 + w * 16 + l16) * QKVN + h * DHEAD;
  bf16x8 q0 = *(const bf16x8*)&qkv[qoff + quad * 8];
  bf16x8 q1 = *(const bf16x8*)&qkv[qoff + 32 + quad * 8];

  const float rw0 = rel_w[h * 3 + 0], rw1 = rel_w[h * 3 + 1], rw2 = rel_w[h * 3 + 2];
  const float rb = rel_b[h];

  f32x4 o[4] = {};
  float m_r[4], l_r[4];
#pragma unroll
  for (int r = 0; r < 4; r++) { m_r[r] = -1e30f; l_r[r] = 0.0f; }

  const int sr = tid >> 3, sg = tid & 7;
  const size_t kbase = (size_t)b * NSEQ * QKVN + DMODEL + h * DHEAD;       // K columns

  // cd base for this lane's C-fragment columns: row0 = quad-row base, col = l16
  const int row0 = it * 64 + w * 16 + quad * 4;
  const float* cdp = cd + (size_t)b * 3 * NN + (size_t)row0 * NSEQ + l16;

  // prefetch cd for jt=0 into registers (48 regs)
  float cdr[3][4][4];
#pragma unroll
  for (int ch = 0; ch < 3; ch++)
#pragma unroll
    for (int ct = 0; ct < 4; ct++)
#pragma unroll
      for (int r = 0; r < 4; r++)
        cdr[ch][ct][r] = cdp[ch * NN + r * NSEQ + ct * 16];

  for (int jt = 0; jt < 32; jt++) {
    // ---- stage K tile and V^T tile (V^T cols XOR-swizzled by d-row bits) ----
#pragma unroll
    for (int rep = 0; rep < 2; rep++) {
      int jrel = sr + rep * 32;
      const bf16_t* kptr = &qkv[kbase + (size_t)(jt * 64 + jrel) * QKVN + sg * 8];
      *(uint4*)&Ks[jrel][sg * 8] = *(const uint4*)kptr;
      union { bf16_t b[8]; uint4 u; } vt;
      vt.u = *(const uint4*)(kptr + DMODEL);   // V = K + 512 cols
      const int pc = jrel ^ ((sg & 3) << 3);   // swizzle: f(row)= ((row>>3)&3)<<3, row=sg*8+e
#pragma unroll
      for (int e = 0; e < 8; e++) Vts[sg * 8 + e][pc] = vt.b[e];
    }
    __syncthreads();

    // ---- S = Q * K^T (wave: 16 rows x 64 cols) ----
    f32x4 s[4] = {};
#pragma unroll
    for (int ct = 0; ct < 4; ct++) {
      bf16x8 b0 = *(const bf16x8*)&Ks[ct * 16 + l16][quad * 8];
      bf16x8 b1 = *(const bf16x8*)&Ks[ct * 16 + l16][32 + quad * 8];
      s[ct] = __builtin_amdgcn_mfma_f32_16x16x32_bf16(q0, b0, s[ct], 0, 0, 0);
      s[ct] = __builtin_amdgcn_mfma_f32_16x16x32_bf16(q1, b1, s[ct], 0, 0, 0);
    }

    // ---- scale + conv bias from prefetched regs (fp32) ----
#pragma unroll
    for (int ct = 0; ct < 4; ct++)
#pragma unroll
      for (int r = 0; r < 4; r++)
        s[ct][r] = s[ct][r] * SCALE_ +
                   (rw0 * cdr[0][ct][r] + rw1 * cdr[1][ct][r] + rw2 * cdr[2][ct][r] + rb);

    // ---- issue cd prefetch for next j-tile (overlaps softmax/PV/staging/QK) ----
    {
      const int jb = (jt < 31 ? jt + 1 : jt) * 64;
#pragma unroll
      for (int ch = 0; ch < 3; ch++)
#pragma unroll
        for (int ct = 0; ct < 4; ct++)
#pragma unroll
          for (int r = 0; r < 4; r++)
            cdr[ch][ct][r] = cdp[ch * NN + r * NSEQ + jb + ct * 16];
    }

    // ---- online softmax (per quad-row; stats across 16 lanes of quad) ----
#pragma unroll
    for (int r = 0; r < 4; r++) {
      float mx = fmaxf(fmaxf(s[0][r], s[1][r]), fmaxf(s[2][r], s[3][r]));
#pragma unroll
      for (int off = 8; off >= 1; off >>= 1) mx = fmaxf(mx, __shfl_xor(mx, off, 64));
      float mnew = fmaxf(m_r[r], mx);
      float alpha = __expf(m_r[r] - mnew);
      float rsum = 0.0f;
#pragma unroll
      for (int ct = 0; ct < 4; ct++) {
        float p = __expf(s[ct][r] - mnew);
        s[ct][r] = p; rsum += p;
      }
#pragma unroll
      for (int off = 8; off >= 1; off >>= 1) rsum += __shfl_xor(rsum, off, 64);
      l_r[r] = l_r[r] * alpha + rsum;
      m_r[r] = mnew;
#pragma unroll
      for (int dt = 0; dt < 4; dt++) o[dt][r] *= alpha;
    }

    // ---- P: C-layout -> LDS (swizzled) -> A-layout (wave-private slice) ----
#pragma unroll
    for (int ct = 0; ct < 4; ct++)
#pragma unroll
      for (int rr = 0; rr < 4; rr++)
        Ps[w * 16 + quad * 4 + rr][(ct * 16 + l16) ^ (quad << 3)] = (bf16_t)s[ct][rr];

    const int psw = ((l16 >> 2) & 3) << 3;          // f(row)=((row>>2)&3)<<3, row=w*16+l16
    bf16x8 p0 = *(const bf16x8*)&Ps[w * 16 + l16][(quad * 8) ^ psw];
    bf16x8 p1 = *(const bf16x8*)&Ps[w * 16 + l16][32 + ((quad * 8) ^ psw)];
#pragma unroll
    for (int dt = 0; dt < 4; dt++) {
      const int row = dt * 16 + l16;
      const int vsw = ((row >> 3) & 3) << 3;        // f(row)=((row>>3)&3)<<3
      bf16x8 v0 = *(const bf16x8*)&Vts[row][(quad * 8) ^ vsw];
      bf16x8 v1 = *(const bf16x8*)&Vts[row][32 + ((quad * 8) ^ vsw)];
      o[dt] = __builtin_amdgcn_mfma_f32_16x16x32_bf16(p0, v0, o[dt], 0, 0, 0);
      o[dt] = __builtin_amdgcn_mfma_f32_16x16x32_bf16(p1, v1, o[dt], 0, 0, 0);
    }
    __syncthreads();   // protect Ks/Vts before next stage
  }

  // ---- epilogue: normalize and store [row, h*64+d] bf16 ----
#pragma unroll
  for (int dt = 0; dt < 4; dt++) {
    int col = h * DHEAD + dt * 16 + l16;
#pragma unroll
    for (int rr = 0; rr < 4; rr++) {
      int row = b * NSEQ + it * 64 + w * 16 + quad * 4 + rr;
      ao[(size_t)row * DMODEL + col] = (bf16_t)(o[dt][rr] / l_r[rr]);
    }
  }
}

// ---------------- launch ----------------
extern "C" void kernel_launch(void* const* d_in, const int* in_sizes, int n_in,
                              void* d_out, int out_size, void* d_ws, size_t ws_size,
                              hipStream_t stream) {
  const float* x     = (const float*)d_in[0];
  const float* cd    = (const float*)d_in[1];
  const float* Wqkv  = (const float*)d_in[2];
  const float* Wout  = (const float*)d_in[3];
  const float* bout  = (const float*)d_in[4];
  const float* rel_w = (const float*)d_in[5];
  const float* rel_b = (const float*)d_in[6];
  float* out = (float*)d_out;

  char* ws = (char*)d_ws;
  const size_t M = (size_t)BATCH * NSEQ;                 // 8192
  bf16_t* xb    = (bf16_t*)ws;                           // 8192*512*2   = 8388608
  bf16_t* WqkvT = (bf16_t*)(ws + 8388608);               // 1536*512*2   = 1572864
  bf16_t* WoutT = (bf16_t*)(ws + 8388608 + 1572864);     // 512*512*2    = 524288
  bf16_t* qkv   = (bf16_t*)(ws + 8388608 + 1572864 + 524288);            // 8192*1536*2 = 25165824
  bf16_t* ao    = (bf16_t*)(ws + 8388608 + 1572864 + 524288 + 25165824); // 8192*512*2  = 8388608

  // converts
  cvt_bf16_kernel<<<(int)(M * DMODEL / 4 / 256), 256, 0, stream>>>(x, xb, (int)(M * DMODEL / 4));
  cvt_transpose_kernel<<<(DMODEL * QKVN) / 256, 256, 0, stream>>>(Wqkv, WqkvT, DMODEL, QKVN);
  cvt_transpose_kernel<<<(DMODEL * DMODEL) / 256, 256, 0, stream>>>(Wout, WoutT, DMODEL, DMODEL);

  // qkv = x @ Wqkv   -> bf16 [8192, 1536]
  gemm_bt_kernel<0, 0><<<dim3(M / 64, QKVN / 64), 256, 0, stream>>>(
      xb, WqkvT, (void*)qkv, nullptr, (int)M, QKVN, DMODEL);

  // fused attention -> ao bf16 [8192, 512]
  attn_kernel<<<BATCH * 32 * HEADS, 256, 0, stream>>>(qkv, cd, rel_w, rel_b, ao);

  // out = ao @ Wout + bout -> fp32 [8192, 512]
  gemm_bt_kernel<1, 1><<<dim3(M / 64, DMODEL / 64), 256, 0, stream>>>(
      ao, WoutT, (void*)out, bout, (int)M, DMODEL, DMODEL);
}

// Round 3
// 443.757 us; speedup vs baseline: 1.3061x; 1.1543x over previous
//
#include <hip/hip_runtime.h>
#include <hip/hip_bf16.h>

typedef __bf16 bf16_t;
typedef __bf16 bf16x8 __attribute__((ext_vector_type(8)));
typedef float f32x4 __attribute__((ext_vector_type(4)));

#define SCALE_ 0.125f   // 64^-0.5
#define BATCH 4
#define NSEQ 2048
#define DMODEL 512
#define HEADS 8
#define DHEAD 64
#define QKVN 1536
#define NN ((size_t)NSEQ * NSEQ)

// LDS-only barrier: does NOT drain vmcnt, so prefetched global loads stay in
// flight across it. All cross-thread communication in attn is via LDS;
// global loads land in private VGPRs (compiler inserts vmcnt waits at use).
#define BAR() asm volatile("s_waitcnt lgkmcnt(0)\n\ts_barrier" ::: "memory")

__device__ __forceinline__ void gload_lds16(const void* g, void* l) {
  __builtin_amdgcn_global_load_lds((const __attribute__((address_space(1))) void*)g,
                                   (__attribute__((address_space(3))) void*)l, 16, 0, 0);
}

__device__ __forceinline__ f32x4 mfma16(bf16x8 a, bf16x8 b, f32x4 c) {
  return __builtin_amdgcn_mfma_f32_16x16x32_bf16(a, b, c, 0, 0, 0);
}

// ---------------- convert kernels ----------------
__global__ __launch_bounds__(256) void cvt_bf16_kernel(const float* __restrict__ in,
                                                       bf16_t* __restrict__ out, int n4) {
  int i = blockIdx.x * 256 + threadIdx.x;
  if (i < n4) {
    float4 v = ((const float4*)in)[i];
    union { bf16_t b[4]; uint2 u; } pk;
    pk.b[0] = (bf16_t)v.x; pk.b[1] = (bf16_t)v.y;
    pk.b[2] = (bf16_t)v.z; pk.b[3] = (bf16_t)v.w;
    ((uint2*)out)[i] = pk.u;
  }
}

// in[R][C] fp32 -> out[C][R] bf16, LDS-tiled so both sides coalesce.
// grid: (C/64, R/64), block 256
__global__ __launch_bounds__(256) void cvt_transpose_kernel(const float* __restrict__ in,
                                                            bf16_t* __restrict__ out, int R, int C) {
  __shared__ float tile[64][65];
  const int r0 = blockIdx.y * 64, c0 = blockIdx.x * 64;
  const int tx = threadIdx.x & 63, tg = threadIdx.x >> 6;
#pragma unroll
  for (int i = 0; i < 16; i++) {
    int rr = tg * 16 + i;
    tile[rr][tx] = in[(size_t)(r0 + rr) * C + c0 + tx];
  }
  __syncthreads();
#pragma unroll
  for (int i = 0; i < 16; i++) {
    int cc = tg * 16 + i;
    out[(size_t)(c0 + cc) * R + r0 + tx] = (bf16_t)tile[tx][cc];
  }
}

// ---------------- GEMM: C[M,N] = A[M,K] * Bt[N,K]^T (+bias) ----------------
// m97-style: 128x128 tile, BK=64, global_load_lds width=16, 4 waves (2x2),
// 4x4 16x16 acc per wave. LDS layout in 16B "slots": slot s holds row=s>>3,
// cg=(s&7)^(row&7) (XOR swizzle applied on the GLOBAL side of the DMA since
// the LDS side is fixed to lane*16B).
template<int BIAS, int OUTF32>
__global__ __launch_bounds__(256) void gemm128_kernel(const bf16_t* __restrict__ A,
    const bf16_t* __restrict__ Bt, void* __restrict__ Cout,
    const float* __restrict__ bias, int M, int N, int K) {
  __shared__ __align__(16) bf16_t As[128 * 64];
  __shared__ __align__(16) bf16_t Bs[128 * 64];
  const int tid = threadIdx.x;
  const int w = tid >> 6, lane = tid & 63, quad = lane >> 4, l16 = lane & 15;
  const int wm = w & 1, wn = w >> 1;
  const int m0 = blockIdx.x * 128, n0 = blockIdx.y * 128;
  f32x4 acc[4][4] = {};
  int srow[4], scg[4];
#pragma unroll
  for (int t = 0; t < 4; t++) {
    int s = (w * 4 + t) * 64 + lane;
    srow[t] = s >> 3;
    scg[t] = (s & 7) ^ (srow[t] & 7);
  }
  for (int k0 = 0; k0 < K; k0 += 64) {
#pragma unroll
    for (int t = 0; t < 4; t++) {
      gload_lds16(&A[(size_t)(m0 + srow[t]) * K + k0 + scg[t] * 8], &As[(w * 4 + t) * 512]);
      gload_lds16(&Bt[(size_t)(n0 + srow[t]) * K + k0 + scg[t] * 8], &Bs[(w * 4 + t) * 512]);
    }
    __syncthreads();   // full drain needed: DMA completion tracked by vmcnt
    bf16x8 af[4][2], bfr[4][2];
#pragma unroll
    for (int mt = 0; mt < 4; mt++) {
      int row = wm * 64 + mt * 16 + l16;
#pragma unroll
      for (int kh = 0; kh < 2; kh++)
        af[mt][kh] = *(const bf16x8*)&As[(row * 8 + ((kh * 4 + quad) ^ (row & 7))) * 8];
    }
#pragma unroll
    for (int nt = 0; nt < 4; nt++) {
      int row = wn * 64 + nt * 16 + l16;
#pragma unroll
      for (int kh = 0; kh < 2; kh++)
        bfr[nt][kh] = *(const bf16x8*)&Bs[(row * 8 + ((kh * 4 + quad) ^ (row & 7))) * 8];
    }
#pragma unroll
    for (int mt = 0; mt < 4; mt++)
#pragma unroll
      for (int nt = 0; nt < 4; nt++) {
        acc[mt][nt] = mfma16(af[mt][0], bfr[nt][0], acc[mt][nt]);
        acc[mt][nt] = mfma16(af[mt][1], bfr[nt][1], acc[mt][nt]);
      }
    __syncthreads();
  }
#pragma unroll
  for (int nt = 0; nt < 4; nt++) {
    int col = n0 + wn * 64 + nt * 16 + l16;
    float bv = BIAS ? bias[col] : 0.0f;
#pragma unroll
    for (int mt = 0; mt < 4; mt++) {
#pragma unroll
      for (int rr = 0; rr < 4; rr++) {
        int row = m0 + wm * 64 + mt * 16 + quad * 4 + rr;
        float v = acc[mt][nt][rr] + bv;
        if (OUTF32) ((float*)Cout)[(size_t)row * N + col] = v;
        else        ((bf16_t*)Cout)[(size_t)row * N + col] = (bf16_t)v;
      }
    }
  }
}

// ---------------- fused flash attention with conv-bias ----------------
// grid: 1024 blocks; bid = h*128 + b*32 + it (head-siblings -> same XCD)
// Register-pipelined K/V staging + combined-at-load cd bias prefetch.
__global__ __launch_bounds__(256, 4) void attn_kernel(const bf16_t* __restrict__ qkv,
    const float* __restrict__ cd, const float* __restrict__ rel_w,
    const float* __restrict__ rel_b, bf16_t* __restrict__ ao) {
  __shared__ __align__(16) bf16_t Ks[64][72];   // K tile: [jrel][d]
  __shared__ __align__(16) bf16_t Vts[64][72];  // V^T tile: [d][j], col XOR-swizzled
  __shared__ __align__(16) bf16_t Ps[64][72];   // P: [qrow][j], col XOR-swizzled
  const int tid = threadIdx.x;
  const int w = tid >> 6, lane = tid & 63, quad = lane >> 4, l16 = lane & 15;
  const int bid = blockIdx.x;
  const int h = bid >> 7, b = (bid >> 5) & 3, it = bid & 31;

  const size_t qoff = (size_t)(b * NSEQ + it * 64 + w * 16 + l16) * QKVN + h * DHEAD;
  bf16x8 q0 = *(const bf16x8*)&qkv[qoff + quad * 8];
  bf16x8 q1 = *(const bf16x8*)&qkv[qoff + 32 + quad * 8];

  const float rw0 = rel_w[h * 3 + 0], rw1 = rel_w[h * 3 + 1], rw2 = rel_w[h * 3 + 2];
  const float rb = rel_b[h];

  f32x4 o[4] = {};
  float m_r[4], l_r[4];
#pragma unroll
  for (int r = 0; r < 4; r++) { m_r[r] = -1e30f; l_r[r] = 0.0f; }

  const int sr = tid >> 3, sg = tid & 7;
  const size_t kbase = (size_t)b * NSEQ * QKVN + DMODEL + h * DHEAD;

  // cd -> bias combined at load: 16 live regs instead of 48
  const int row0 = it * 64 + w * 16 + quad * 4;
  const float* cdp = cd + (size_t)b * 3 * NN + (size_t)row0 * NSEQ + l16;
  float biasr[4][4];
#define LOADBIAS(JT) do { const int jb_ = (JT) * 64;                                   \
  _Pragma("unroll") for (int ct_ = 0; ct_ < 4; ct_++)                                  \
  _Pragma("unroll") for (int r_ = 0; r_ < 4; r_++) {                                   \
    size_t ci_ = (size_t)r_ * NSEQ + jb_ + ct_ * 16;                                   \
    biasr[ct_][r_] = fmaf(rw0, cdp[ci_],                                               \
                     fmaf(rw1, cdp[ci_ + NN], fmaf(rw2, cdp[ci_ + 2 * NN], rb)));      \
  } } while (0)

  // prologue: K/V tile 0 -> regs, bias tile 0 -> regs
  uint4 k0r, k1r, v0r, v1r;
  {
    const bf16_t* p = &qkv[kbase + (size_t)sr * QKVN + sg * 8];
    k0r = *(const uint4*)p;               v0r = *(const uint4*)(p + DMODEL);
    k1r = *(const uint4*)(p + 32 * QKVN); v1r = *(const uint4*)(p + 32 * QKVN + DMODEL);
  }
  LOADBIAS(0);

  for (int jt = 0; jt < 32; jt++) {
    // ---- staged regs -> LDS (loads had a full compute phase to land) ----
    *(uint4*)&Ks[sr][sg * 8]      = k0r;
    *(uint4*)&Ks[sr + 32][sg * 8] = k1r;
    {
      union { bf16_t e[8]; uint4 u; } va, vb; va.u = v0r; vb.u = v1r;
      const int pc = sr ^ ((sg & 3) << 3);
#pragma unroll
      for (int e2 = 0; e2 < 8; e2++) {
        Vts[sg * 8 + e2][pc]      = va.e[e2];
        Vts[sg * 8 + e2][pc + 32] = vb.e[e2];
      }
    }
    BAR();

    // ---- issue next tile's K/V loads (in flight across the whole phase) ----
    if (jt < 31) {
      const bf16_t* p = &qkv[kbase + (size_t)((jt + 1) * 64 + sr) * QKVN + sg * 8];
      k0r = *(const uint4*)p;               v0r = *(const uint4*)(p + DMODEL);
      k1r = *(const uint4*)(p + 32 * QKVN); v1r = *(const uint4*)(p + 32 * QKVN + DMODEL);
    }

    // ---- S = Q * K^T ----
    f32x4 s[4] = {};
#pragma unroll
    for (int ct = 0; ct < 4; ct++) {
      bf16x8 b0 = *(const bf16x8*)&Ks[ct * 16 + l16][quad * 8];
      bf16x8 b1 = *(const bf16x8*)&Ks[ct * 16 + l16][32 + quad * 8];
      s[ct] = mfma16(q0, b0, s[ct]);
      s[ct] = mfma16(q1, b1, s[ct]);
    }

    // ---- scale + bias (prefetched), then prefetch next bias ----
#pragma unroll
    for (int ct = 0; ct < 4; ct++)
#pragma unroll
      for (int r = 0; r < 4; r++)
        s[ct][r] = s[ct][r] * SCALE_ + biasr[ct][r];
    if (jt < 31) LOADBIAS(jt + 1);

    // ---- online softmax (per quad-row) ----
#pragma unroll
    for (int r = 0; r < 4; r++) {
      float mx = fmaxf(fmaxf(s[0][r], s[1][r]), fmaxf(s[2][r], s[3][r]));
#pragma unroll
      for (int off = 8; off >= 1; off >>= 1) mx = fmaxf(mx, __shfl_xor(mx, off, 64));
      float mnew = fmaxf(m_r[r], mx);
      float alpha = __expf(m_r[r] - mnew);
      float rsum = 0.0f;
#pragma unroll
      for (int ct = 0; ct < 4; ct++) {
        float p = __expf(s[ct][r] - mnew);
        s[ct][r] = p; rsum += p;
      }
#pragma unroll
      for (int off = 8; off >= 1; off >>= 1) rsum += __shfl_xor(rsum, off, 64);
      l_r[r] = l_r[r] * alpha + rsum;
      m_r[r] = mnew;
#pragma unroll
      for (int dt = 0; dt < 4; dt++) o[dt][r] *= alpha;
    }

    // ---- P: C-layout -> LDS (swizzled) -> A-layout (wave-private slice) ----
#pragma unroll
    for (int ct = 0; ct < 4; ct++)
#pragma unroll
      for (int rr = 0; rr < 4; rr++)
        Ps[w * 16 + quad * 4 + rr][(ct * 16 + l16) ^ (quad << 3)] = (bf16_t)s[ct][rr];

    const int psw = ((l16 >> 2) & 3) << 3;
    bf16x8 p0 = *(const bf16x8*)&Ps[w * 16 + l16][(quad * 8) ^ psw];
    bf16x8 p1 = *(const bf16x8*)&Ps[w * 16 + l16][32 + ((quad * 8) ^ psw)];
#pragma unroll
    for (int dt = 0; dt < 4; dt++) {
      const int row = dt * 16 + l16;
      const int vsw = ((row >> 3) & 3) << 3;
      bf16x8 v0 = *(const bf16x8*)&Vts[row][(quad * 8) ^ vsw];
      bf16x8 v1 = *(const bf16x8*)&Vts[row][32 + ((quad * 8) ^ vsw)];
      o[dt] = mfma16(p0, v0, o[dt]);
      o[dt] = mfma16(p1, v1, o[dt]);
    }
    BAR();   // readers of Ks/Vts done before next iteration's writes
  }

  // ---- epilogue ----
#pragma unroll
  for (int dt = 0; dt < 4; dt++) {
    int col = h * DHEAD + dt * 16 + l16;
#pragma unroll
    for (int rr = 0; rr < 4; rr++) {
      int row = b * NSEQ + it * 64 + w * 16 + quad * 4 + rr;
      ao[(size_t)row * DMODEL + col] = (bf16_t)(o[dt][rr] / l_r[rr]);
    }
  }
#undef LOADBIAS
}

// ---------------- launch ----------------
extern "C" void kernel_launch(void* const* d_in, const int* in_sizes, int n_in,
                              void* d_out, int out_size, void* d_ws, size_t ws_size,
                              hipStream_t stream) {
  const float* x     = (const float*)d_in[0];
  const float* cd    = (const float*)d_in[1];
  const float* Wqkv  = (const float*)d_in[2];
  const float* Wout  = (const float*)d_in[3];
  const float* bout  = (const float*)d_in[4];
  const float* rel_w = (const float*)d_in[5];
  const float* rel_b = (const float*)d_in[6];
  float* out = (float*)d_out;

  char* ws = (char*)d_ws;
  const size_t M = (size_t)BATCH * NSEQ;                 // 8192
  bf16_t* xb    = (bf16_t*)ws;                           // 8 MB
  bf16_t* WqkvT = (bf16_t*)(ws + 8388608);
  bf16_t* WoutT = (bf16_t*)(ws + 8388608 + 1572864);
  bf16_t* qkv   = (bf16_t*)(ws + 8388608 + 1572864 + 524288);
  bf16_t* ao    = (bf16_t*)(ws + 8388608 + 1572864 + 524288 + 25165824);

  cvt_bf16_kernel<<<(int)(M * DMODEL / 4 / 256), 256, 0, stream>>>(x, xb, (int)(M * DMODEL / 4));
  cvt_transpose_kernel<<<dim3(QKVN / 64, DMODEL / 64), 256, 0, stream>>>(Wqkv, WqkvT, DMODEL, QKVN);
  cvt_transpose_kernel<<<dim3(DMODEL / 64, DMODEL / 64), 256, 0, stream>>>(Wout, WoutT, DMODEL, DMODEL);

  gemm128_kernel<0, 0><<<dim3(M / 128, QKVN / 128), 256, 0, stream>>>(
      xb, WqkvT, (void*)qkv, nullptr, (int)M, QKVN, DMODEL);

  attn_kernel<<<BATCH * 32 * HEADS, 256, 0, stream>>>(qkv, cd, rel_w, rel_b, ao);

  gemm128_kernel<1, 1><<<dim3(M / 128, DMODEL / 128), 256, 0, stream>>>(
      ao, WoutT, (void*)out, bout, (int)M, DMODEL, DMODEL);
}